// Round 2
// baseline (160.040 us; speedup 1.0000x reference)
//
#include <hip/hip_runtime.h>
#include <hip/hip_bf16.h>

// QuIP#-style quantized linear:
//   xh = fwht(x*SU)/sqrt(8192); W = cb[Qidxs]; z = xh @ W^T;
//   out = fwht(z)/sqrt(8192) * SV * Wscale
// bf16 MFMA GEMM with on-the-fly codebook decompression: B-fragment of
// mfma_f32_16x16x32_bf16 lane(quad,l16) = B[8*quad+j][l16] = one 16 B
// codebook entry -> one gather per lane per k-tile.

typedef __attribute__((ext_vector_type(4))) float f32x4;
typedef __attribute__((ext_vector_type(8))) __bf16 bf16x8;
typedef __attribute__((ext_vector_type(4))) __bf16 bf16x4;

#define IN_F 8192
#define OUT_F 8192
#define TOKENS 32
#define INV_SQRT_8192 0.011048543456039806f

// LDS padding: +1 float per 32 (breaks stride-32 conflicts in FWHT passes)
#define PAD(i) ((i) + ((i) >> 5))

// ---------------- register FWHT helpers ----------------
__device__ inline void fwht32_reg(float* r) {
    #pragma unroll
    for (int h = 1; h < 32; h <<= 1) {
        #pragma unroll
        for (int i = 0; i < 32; i += 2 * h) {
            #pragma unroll
            for (int j = 0; j < h; ++j) {
                float a = r[i + j], b = r[i + j + h];
                r[i + j] = a + b;
                r[i + j + h] = a - b;
            }
        }
    }
}

// FWHT over 8192 elements living in padded LDS, 256 threads.
// 3 register passes: bits0-4, bits5-9, bits10-12. Caller syncs before call.
__device__ inline void fwht8192_lds(float* s, int tid) {
    float r[32];
    // pass 1: i = tid*32 + j  (bits 0-4); addr 33*tid+j -> conflict-free
    int b1 = tid * 32;
    #pragma unroll
    for (int j = 0; j < 32; ++j) r[j] = s[PAD(b1 + j)];
    fwht32_reg(r);
    #pragma unroll
    for (int j = 0; j < 32; ++j) s[PAD(b1 + j)] = r[j];
    __syncthreads();
    // pass 2: i = (tid&31) + (tid>>5)*1024 + 32*j  (bits 5-9); 2-way max
    int b2 = (tid & 31) + (tid >> 5) * 1024;
    #pragma unroll
    for (int j = 0; j < 32; ++j) r[j] = s[PAD(b2 + 32 * j)];
    fwht32_reg(r);
    #pragma unroll
    for (int j = 0; j < 32; ++j) s[PAD(b2 + 32 * j)] = r[j];
    __syncthreads();
    // pass 3: i = tid*4 + jj + 1024*k  (bits 10-12), 4 groups of FWHT-8
    #pragma unroll
    for (int jj = 0; jj < 4; ++jj) {
        float g[8];
        int b3 = tid * 4 + jj;
        #pragma unroll
        for (int k = 0; k < 8; ++k) g[k] = s[PAD(b3 + 1024 * k)];
        #pragma unroll
        for (int h = 1; h < 8; h <<= 1) {
            #pragma unroll
            for (int i = 0; i < 8; i += 2 * h) {
                #pragma unroll
                for (int j = 0; j < h; ++j) {
                    float a = g[i + j], b = g[i + j + h];
                    g[i + j] = a + b;
                    g[i + j + h] = a - b;
                }
            }
        }
        #pragma unroll
        for (int k = 0; k < 8; ++k) s[PAD(b3 + 1024 * k)] = g[k];
    }
    __syncthreads();
}

// ---------------- kernel 1: fused codebook cvt + input FWHT ----------------
// blocks 0..511: cb fp32 -> bf16.  blocks 512..543: per-token fwht(x*SU)->bf16
__global__ __launch_bounds__(256)
void prep_kernel(const float* __restrict__ cb, __bf16* __restrict__ cbb,
                 const float* __restrict__ x, const float* __restrict__ su,
                 __bf16* __restrict__ xh) {
    __shared__ float s[8192 + 256];
    const int tid = threadIdx.x;
    if (blockIdx.x < 512) {
        int i = blockIdx.x * 256 + tid;          // 131072 float4s total
        float4 v = ((const float4*)cb)[i];
        bf16x4 o;
        o[0] = (__bf16)v.x; o[1] = (__bf16)v.y;
        o[2] = (__bf16)v.z; o[3] = (__bf16)v.w;
        ((bf16x4*)cbb)[i] = o;
        return;
    }
    const int t = blockIdx.x - 512;
    #pragma unroll
    for (int i = tid; i < IN_F; i += 256)
        s[PAD(i)] = x[t * IN_F + i] * su[i];
    __syncthreads();
    fwht8192_lds(s, tid);
    #pragma unroll
    for (int i = tid; i < IN_F; i += 256)
        xh[t * IN_F + i] = (__bf16)(s[PAD(i)] * INV_SQRT_8192);
}

// ---------------- kernel 2: z = xh @ W^T with on-the-fly decompress --------
template <int KS>
__global__ __launch_bounds__(256, 4)
void qgemm_kernel(const int* __restrict__ qidxs,
                  const __bf16* __restrict__ cb,
                  const __bf16* __restrict__ xh,
                  float* __restrict__ zpart) {
    constexpr int KCHUNK = IN_F / KS;
    constexpr int NKT = KCHUNK / 32;             // k-tiles of 32 per wave
    constexpr int G = NKT / 8;                   // pipeline groups
    const int ks   = blockIdx.x % KS;
    const int nb   = blockIdx.x / KS;            // 0..127
    const int wave = threadIdx.x >> 6;
    const int lane = threadIdx.x & 63;
    const int quad = lane >> 4;
    const int l16  = lane & 15;
    const int n = nb * 64 + wave * 16 + l16;     // output feature

    const int* qp = qidxs + (size_t)n * (IN_F / 8) + ks * (KCHUNK / 8);
    const bf16x8* a0p = (const bf16x8*)(xh + l16 * IN_F + ks * KCHUNK + quad * 8);
    const bf16x8* a1p = (const bf16x8*)(xh + (l16 + 16) * IN_F + ks * KCHUNK + quad * 8);
    const bf16x8* cbv = (const bf16x8*)cb;

    f32x4 acc0 = {0.f, 0.f, 0.f, 0.f};
    f32x4 acc1 = {0.f, 0.f, 0.f, 0.f};

    int idx[8];
    #pragma unroll
    for (int j = 0; j < 8; ++j) idx[j] = qp[j * 4 + quad];

    #pragma unroll 1
    for (int g = 0; g < G; ++g) {
        // prefetch next group's indices (last group re-reads its own - safe)
        const int po = (g + 1 < G ? g + 1 : g) * 32;
        int nidx[8];
        #pragma unroll
        for (int j = 0; j < 8; ++j) nidx[j] = qp[po + j * 4 + quad];
        #pragma unroll
        for (int j = 0; j < 8; ++j) {
            bf16x8 b = cbv[idx[j]];              // 16 B gather = B fragment
            bf16x8 a0 = a0p[(g * 8 + j) * 4];
            bf16x8 a1 = a1p[(g * 8 + j) * 4];
            acc0 = __builtin_amdgcn_mfma_f32_16x16x32_bf16(a0, b, acc0, 0, 0, 0);
            acc1 = __builtin_amdgcn_mfma_f32_16x16x32_bf16(a1, b, acc1, 0, 0, 0);
        }
        #pragma unroll
        for (int j = 0; j < 8; ++j) idx[j] = nidx[j];
    }

    // D layout: D[m=quad*4+r][n=l16]
    float* zp = zpart + (size_t)ks * TOKENS * OUT_F + n;
    #pragma unroll
    for (int r = 0; r < 4; ++r) {
        zp[(quad * 4 + r) * OUT_F] = acc0[r];
        zp[(16 + quad * 4 + r) * OUT_F] = acc1[r];
    }
}

// ---------------- kernel 3: out = fwht(sum zpart)/sqrt(n) * SV * Wscale ----
template <int KS>
__global__ __launch_bounds__(256)
void had_out_kernel(const float* __restrict__ zpart,
                    const float* __restrict__ sv,
                    const float* __restrict__ wscale,
                    float* __restrict__ out) {
    __shared__ float s[8192 + 256];
    const int t = blockIdx.x;
    const int tid = threadIdx.x;
    #pragma unroll
    for (int i = tid; i < OUT_F; i += 256) {
        float acc = 0.f;
        #pragma unroll
        for (int k = 0; k < KS; ++k)
            acc += zpart[((size_t)k * TOKENS + t) * OUT_F + i];
        s[PAD(i)] = acc;
    }
    __syncthreads();
    fwht8192_lds(s, tid);
    const float sc = INV_SQRT_8192 * wscale[0];
    #pragma unroll
    for (int i = tid; i < OUT_F; i += 256)
        out[t * OUT_F + i] = s[PAD(i)] * sc * sv[i];
}

extern "C" void kernel_launch(void* const* d_in, const int* in_sizes, int n_in,
                              void* d_out, int out_size, void* d_ws, size_t ws_size,
                              hipStream_t stream) {
    const float* x      = (const float*)d_in[0];   // (32, 8192)
    const float* cb     = (const float*)d_in[1];   // (65536, 8)
    const int*   qidxs  = (const int*)d_in[2];     // (8192, 1024)
    const float* su     = (const float*)d_in[3];   // (8192,)
    const float* sv     = (const float*)d_in[4];   // (8192,)
    const float* wscale = (const float*)d_in[5];   // scalar
    float* out = (float*)d_out;                    // (32, 8192) fp32

    char* ws = (char*)d_ws;
    __bf16* cb_bf16 = (__bf16*)ws;                               // 1 MB
    __bf16* xh      = (__bf16*)(ws + (1u << 20));                // 512 KB
    float*  zpart   = (float*)(ws + (1u << 20) + (512u << 10));

    const size_t need8 = (1u << 20) + (512u << 10) +
                         (size_t)8 * TOKENS * OUT_F * 4;         // ~9.9 MB
    const bool big = ws_size >= need8;

    hipLaunchKernelGGL(prep_kernel, dim3(544), dim3(256), 0, stream,
                       cb, cb_bf16, x, su, xh);
    if (big) {
        hipLaunchKernelGGL((qgemm_kernel<8>), dim3(128 * 8), dim3(256), 0,
                           stream, qidxs, cb_bf16, xh, zpart);
        hipLaunchKernelGGL((had_out_kernel<8>), dim3(TOKENS), dim3(256), 0,
                           stream, zpart, sv, wscale, out);
    } else {
        hipLaunchKernelGGL((qgemm_kernel<4>), dim3(128 * 4), dim3(256), 0,
                           stream, qidxs, cb_bf16, xh, zpart);
        hipLaunchKernelGGL((had_out_kernel<4>), dim3(TOKENS), dim3(256), 0,
                           stream, zpart, sv, wscale, out);
    }
}